// Round 4
// baseline (117.986 us; speedup 1.0000x reference)
//
#include <hip/hip_runtime.h>

// DepthToSpace 3D, block=2, channels_last.
// in:  (4, 32, 64, 64, 128) fp32   out: (4, 64, 128, 128, 16) fp32
// out[n, 2z+dz, 2y+dy, 2x+dx, c] = in[n, z, y, x, (dz*4+dy*2+dx)*16 + c]
//
// Pure permutation, memory-bound. One float4 per (thread, iter); 4 iters
// per thread (independent -> 4 outstanding loads). NO nontemporal hints:
// R3 A/B showed nt+coarsen regressed 95.4 -> 106.5 us; this isolates nt.

typedef float f32x4 __attribute__((ext_vector_type(4)));

__global__ __launch_bounds__(256) void d2s_kernel(const f32x4* __restrict__ in4,
                                                  f32x4* __restrict__ out4) {
    constexpr unsigned int N4 = 16777216u;      // out_size / 4
    constexpr unsigned int STRIDE = N4 / 4u;    // 4 iterations per thread
    unsigned int base = blockIdx.x * 256u + threadIdx.x;

#pragma unroll
    for (int it = 0; it < 4; ++it) {
        unsigned int idx = base + (unsigned int)it * STRIDE;

        // Output float4 index decomposition.
        // out float layout: (n, Z(64), Y(128), X(128), c(16)) -> float4: c4 in [0,4)
        unsigned int c4 = idx & 3u;
        unsigned int t  = idx >> 2;
        unsigned int X  = t & 127u;  t >>= 7;
        unsigned int Y  = t & 127u;  t >>= 7;
        unsigned int Z  = t & 63u;
        unsigned int n  = t >> 6;

        unsigned int x = X >> 1, dx = X & 1u;
        unsigned int y = Y >> 1, dy = Y & 1u;
        unsigned int z = Z >> 1, dz = Z & 1u;
        unsigned int i = dz * 4u + dy * 2u + dx;

        // input float4 index: (((n*32+z)*64+y)*64+x)*32 + i*4 + c4
        unsigned int in_idx = ((((n * 32u + z) * 64u + y) * 64u + x) << 5) + (i << 2) + c4;

        out4[idx] = in4[in_idx];
    }
}

extern "C" void kernel_launch(void* const* d_in, const int* in_sizes, int n_in,
                              void* d_out, int out_size, void* d_ws, size_t ws_size,
                              hipStream_t stream) {
    const f32x4* in4 = (const f32x4*)d_in[0];
    f32x4* out4 = (f32x4*)d_out;
    // 16,777,216 float4 total / 4 per thread / 256 per block = 16384 blocks
    int block = 256;
    int grid = 16384;
    d2s_kernel<<<grid, block, 0, stream>>>(in4, out4);
}

// Round 5
// 98.990 us; speedup vs baseline: 1.1919x; 1.1919x over previous
//
#include <hip/hip_runtime.h>

// DepthToSpace 3D, block=2, channels_last.
// in:  (4, 32, 64, 64, 128) fp32   out: (4, 64, 128, 128, 16) fp32
// out[n, 2z+dz, 2y+dy, 2x+dx, c] = in[n, z, y, x, (dz*4+dy*2+dx)*16 + c]
//
// LDS-staged variant: one block per input line (n,z,y) = 2048 float4 = 32KB.
//  - read: fully sequential 32KB per block (1KB per wave-instruction)
//  - write: 4 contiguous 8KB output rows (Z=2z+dz, Y=2y+dy)
//  - shuffle done in LDS; XOR swizzle (s ^ (x&31)) within each x-group makes
//    both ds_write_b128 and ds_read_b128 conflict-free (each 8-lane group
//    covers all 8 bank-quads).
// R1 (direct, strided-128B reads) = 95.4us; this tests whether read
// sequentiality buys the remaining ~10% to the 6.3 TB/s copy ceiling.

typedef float f32x4 __attribute__((ext_vector_type(4)));

__global__ __launch_bounds__(256) void d2s_lds(const f32x4* __restrict__ in4,
                                               f32x4* __restrict__ out4) {
    __shared__ f32x4 lds[2048];   // 32 KB

    unsigned int b = blockIdx.x;          // b = (n*32 + z)*64 + y
    unsigned int t = threadIdx.x;
    unsigned int n = b >> 11;
    unsigned int z = (b >> 6) & 31u;
    unsigned int y = b & 63u;

    const f32x4* src = in4 + ((size_t)b << 11);   // 2048 f4 per line

    // 1) sequential read of the whole line into registers (8 f4/thread)
    f32x4 v[8];
#pragma unroll
    for (int j = 0; j < 8; ++j) v[j] = src[t + 256u * j];

    // 2) stage to LDS, swizzled: p = x*32 + s, slot = x*32 + (s ^ (x&31))
#pragma unroll
    for (int j = 0; j < 8; ++j) {
        unsigned int p = t + 256u * j;
        unsigned int x = p >> 5;
        unsigned int s = p & 31u;
        lds[(x << 5) | (s ^ (x & 31u))] = v[j];
    }
    __syncthreads();

    // 3) write 4 output rows; q enumerates (r, X, c4) with r=(dz,dy)
    unsigned int Zb = z << 1, Yb = y << 1;
#pragma unroll
    for (int j = 0; j < 8; ++j) {
        unsigned int q = t + 256u * j;          // 0..2047
        unsigned int r = q >> 9;                // dz = r>>1, dy = r&1
        unsigned int rem = q & 511u;            // X*4 + c4
        unsigned int c4 = rem & 3u;
        unsigned int X = rem >> 2;
        unsigned int x = X >> 1, dx = X & 1u;
        unsigned int i = (r << 1) | dx;         // dz*4 + dy*2 + dx
        unsigned int s = (i << 2) | c4;
        f32x4 val = lds[(x << 5) | (s ^ (x & 31u))];

        unsigned int Z = Zb + (r >> 1);
        unsigned int Y = Yb + (r & 1u);
        unsigned int oidx = ((((n << 6) + Z) << 7) + Y);   // (n*64+Z)*128 + Y
        out4[((size_t)oidx << 9) + rem] = val;             // *512 + rem
    }
}

extern "C" void kernel_launch(void* const* d_in, const int* in_sizes, int n_in,
                              void* d_out, int out_size, void* d_ws, size_t ws_size,
                              hipStream_t stream) {
    const f32x4* in4 = (const f32x4*)d_in[0];
    f32x4* out4 = (f32x4*)d_out;
    int block = 256;
    int grid = 8192;   // 4*32*64 input lines
    d2s_lds<<<grid, block, 0, stream>>>(in4, out4);
}